// Round 11
// baseline (401.333 us; speedup 1.0000x reference)
//
#include <hip/hip_runtime.h>
#include <stdint.h>

#define NN 50000
#define NE 500000
#define NEB ((NE + 127) / 128)
#define SST 136   // LDS row stride in shorts (272 B -> 2-way banks on b128 reads)

#define BARRIER() asm volatile("s_waitcnt lgkmcnt(0)\n\ts_barrier" ::: "memory")
#define WAVE_SYNC() asm volatile("s_waitcnt lgkmcnt(0)" ::: "memory")

typedef __attribute__((ext_vector_type(8))) short bf16x8;
typedef __attribute__((ext_vector_type(4))) float f32x4;

// fast silu: x * v_rcp(1+e^-x). 1-instr rcp vs ~8-instr IEEE div; +-1 ulp. (R6)
__device__ __forceinline__ float silu(float x) {
    float e = __expf(-x);
    return x * __builtin_amdgcn_rcpf(1.0f + e);
}
__device__ __forceinline__ float bf2f(unsigned short s) {
    union { unsigned int u; float f; } v; v.u = ((unsigned int)s) << 16; return v.f;
}
__device__ __forceinline__ float bflo(unsigned int u) {   // low bf16 of packed pair
    union { unsigned int u; float f; } v; v.u = u << 16; return v.f;
}
__device__ __forceinline__ float bfhi(unsigned int u) {   // high bf16 of packed pair
    union { unsigned int u; float f; } v; v.u = u & 0xffff0000u; return v.f;
}
__device__ __forceinline__ unsigned short f2bf(float f) {   // RNE (prep only)
    union { float f; unsigned int u; } v; v.f = f;
    return (unsigned short)((v.u + 0x7fffu + ((v.u >> 16) & 1u)) >> 16);
}
// HW packed f32->bf16 (RNE): 1 instr
__device__ __forceinline__ unsigned int pack2(float a, float b) {
    unsigned int r;
    asm("v_cvt_pk_bf16_f32 %0, %1, %2" : "=v"(r) : "v"(a), "v"(b));
    return r;
}
__device__ __forceinline__ bf16x8 packf8(const float* p) {
    float4 f0 = *(const float4*)p; float4 f1 = *(const float4*)(p + 4);
    union { bf16x8 v; unsigned int u[4]; } o;
    o.u[0] = pack2(f0.x, f0.y); o.u[1] = pack2(f0.z, f0.w);
    o.u[2] = pack2(f1.x, f1.y); o.u[3] = pack2(f1.z, f1.w);
    return o.v;
}

// ---------------- prep ----------------
__global__ void prep_h(const float* __restrict__ h, unsigned short* __restrict__ hb) {
    int i = blockIdx.x * 256 + threadIdx.x;
    if (i < NN * 128 / 4) {
        float4 v = ((const float4*)h)[i];
        uint2 o; o.x = pack2(v.x, v.y); o.y = pack2(v.z, v.w);
        ((uint2*)hb)[i] = o;
    }
}

// B^T layouts. sigma(col) = (col%16)*8 + col/16 ; orig_k(ks) = (ks%8)*16 + ks/8
__global__ void prep_w(const float* __restrict__ We1, const float* __restrict__ We2,
                       const float* __restrict__ Wc1, const float* __restrict__ Wv1,
                       const float* __restrict__ Wn1, const float* __restrict__ Wn2,
                       unsigned short* __restrict__ Wt1, unsigned short* __restrict__ Wt2,
                       unsigned short* __restrict__ Wt3, unsigned short* __restrict__ Wv1t,
                       unsigned short* __restrict__ Wn1t, unsigned short* __restrict__ Wn2t) {
    int i = blockIdx.x * 256 + threadIdx.x;
    if (i < 32768) {                                    // Wt1 [128][256] natural
        int j = i >> 8, k = i & 255;
        Wt1[i] = f2bf(We1[k * 128 + j]);
    } else if (i < 49152) {                             // Wt2 [128][128] sigma
        int t = i - 32768; int j = t >> 7, ks = t & 127;
        int k0 = (ks & 7) * 16 + (ks >> 3);
        Wt2[t] = f2bf(We2[k0 * 128 + j]);
    } else if (i < 65536) {                             // Wt3 [128][128] sigma
        int t = i - 49152; int j = t >> 7, ks = t & 127;
        int k0 = (ks & 7) * 16 + (ks >> 3);
        Wt3[t] = f2bf(Wc1[k0 * 128 + j]);
    } else if (i < 81920) {                             // Wv1t [128][128] natural
        int t = i - 65536; int j = t >> 7, k = t & 127;
        Wv1t[t] = f2bf(Wv1[k * 128 + j]);
    } else if (i < 114688) {                            // Wn1t [128][256]: h natural, m sigma
        int t = i - 81920; int j = t >> 8, k = t & 255;
        int ksrc;
        if (k < 128) ksrc = k;
        else { int ks = k - 128; ksrc = 128 + (ks & 7) * 16 + (ks >> 3); }
        Wn1t[t] = f2bf(Wn1[ksrc * 128 + j]);
    } else if (i < 131072) {                            // Wn2t [128][128] sigma
        int t = i - 114688; int j = t >> 7, ks = t & 127;
        int k0 = (ks & 7) * 16 + (ks >> 3);
        Wn2t[t] = f2bf(Wn2[k0 * 128 + j]);
    }
}

// ---------------- CSR build ----------------
__global__ void csr_count(const int* __restrict__ eidx, int* __restrict__ deg) {
    int e = blockIdx.x * 256 + threadIdx.x;
    if (e < NE) atomicAdd(&deg[eidx[e]], 1);
}

__global__ void scan_a(const int* __restrict__ deg, int* __restrict__ bsum) {
    __shared__ int s[256];
    int t = threadIdx.x, idx = blockIdx.x * 256 + t;
    s[t] = (idx < NN) ? deg[idx] : 0;
    __syncthreads();
    for (int off = 128; off > 0; off >>= 1) {
        if (t < off) s[t] += s[t + off];
        __syncthreads();
    }
    if (t == 0) bsum[blockIdx.x] = s[0];
}

__global__ void scan_b(int* __restrict__ bsum) {   // exclusive scan, 196 values
    __shared__ int s[256];
    int t = threadIdx.x;
    int v = (t < 196) ? bsum[t] : 0;
    s[t] = v;
    __syncthreads();
    for (int off = 1; off < 256; off <<= 1) {
        int x = (t >= off) ? s[t - off] : 0;
        __syncthreads();
        s[t] += x;
        __syncthreads();
    }
    if (t < 196) bsum[t] = s[t] - v;
}

__global__ void scan_c(const int* __restrict__ deg, const int* __restrict__ bsum,
                       int* __restrict__ rowptr) {
    __shared__ int s[256];
    int t = threadIdx.x, idx = blockIdx.x * 256 + t;
    int v = (idx < NN) ? deg[idx] : 0;
    s[t] = v;
    __syncthreads();
    for (int off = 1; off < 256; off <<= 1) {
        int x = (t >= off) ? s[t - off] : 0;
        __syncthreads();
        s[t] += x;
        __syncthreads();
    }
    if (idx < NN) rowptr[idx] = bsum[blockIdx.x] + s[t] - v;
    if (idx == 0) rowptr[NN] = NE;
}

__global__ void csr_fill(const int* __restrict__ eidx, const int* __restrict__ rowptr,
                         int* __restrict__ cursor,
                         int* __restrict__ csr_r, int* __restrict__ csr_c) {
    int e = blockIdx.x * 256 + threadIdx.x;
    if (e < NE) {
        int r = eidx[e], c = eidx[NE + e];
        int slot = rowptr[r] + atomicAdd(&cursor[r], 1);
        csr_r[slot] = r; csr_c[slot] = c;
    }
}

// ---------------- helpers (256-thread staging) ----------------
__device__ __forceinline__ void stage256(const unsigned short* __restrict__ W, int halfk,
                                         unsigned short* sW, int tid) {
#pragma unroll
    for (int t = 0; t < 8; ++t) {
        int idx = tid + t * 256; int j = idx >> 4, g = idx & 15;
        *(uint4*)(sW + j * SST + g * 8) = *(const uint4*)(W + (size_t)j * 256 + halfk * 128 + g * 8);
    }
}
__device__ __forceinline__ void stage128(const unsigned short* __restrict__ W,
                                         unsigned short* sW, int tid) {
#pragma unroll
    for (int t = 0; t < 8; ++t) {
        int idx = tid + t * 256; int j = idx >> 4, g = idx & 15;
        *(uint4*)(sW + j * SST + g * 8) = *(const uint4*)(W + (size_t)j * 128 + g * 8);
    }
}
__device__ __forceinline__ void mfma4(const bf16x8 a[2][4], const unsigned short* sW,
                                      int l16, int q, f32x4 acc[2][8]) {
#pragma unroll
    for (int kc = 0; kc < 4; ++kc)
#pragma unroll
        for (int ct = 0; ct < 8; ++ct) {
            bf16x8 b = *(const bf16x8*)(sW + (ct * 16 + l16) * SST + kc * 32 + q * 8);
            acc[0][ct] = __builtin_amdgcn_mfma_f32_16x16x32_bf16(a[0][kc], b, acc[0][ct], 0, 0, 0);
            acc[1][ct] = __builtin_amdgcn_mfma_f32_16x16x32_bf16(a[1][kc], b, acc[1][ct], 0, 0, 0);
        }
}

// ---------------- prep_P: per-NODE halves of e1 ----------------
__global__ __launch_bounds__(256, 2) void prep_P(
    const unsigned short* __restrict__ hb,
    const unsigned short* __restrict__ Wt1,
    unsigned short* __restrict__ P1, unsigned short* __restrict__ P2)
{
    __shared__ __align__(16) unsigned short sWa[128 * SST];
    __shared__ __align__(16) unsigned short sWb[128 * SST];
    const int tid = threadIdx.x;
    const int wv = tid >> 6, lane = tid & 63, q = lane >> 4, l16 = lane & 15;
    const int n0 = blockIdx.x * 128;

    stage256(Wt1, 0, sWa, tid);
    stage256(Wt1, 1, sWb, tid);
    bf16x8 ah[2][4];
#pragma unroll
    for (int si = 0; si < 2; ++si) {
        int nn = n0 + (wv * 2 + si) * 16 + l16; if (nn >= NN) nn = NN - 1;
#pragma unroll
        for (int kc = 0; kc < 4; ++kc)
            ah[si][kc] = *(const bf16x8*)(hb + (size_t)nn * 128 + kc * 32 + q * 8);
    }
    BARRIER();

    f32x4 acc[2][8];
#pragma unroll
    for (int si = 0; si < 2; ++si)
#pragma unroll
        for (int ct = 0; ct < 8; ++ct) acc[si][ct] = (f32x4){0.f, 0.f, 0.f, 0.f};
    mfma4(ah, sWa, l16, q, acc);
#pragma unroll
    for (int si = 0; si < 2; ++si)
#pragma unroll
        for (int r = 0; r < 4; ++r) {
            int n = n0 + (wv * 2 + si) * 16 + q * 4 + r;
            if (n < NN) {
                uint4 pk = make_uint4(pack2(acc[si][0][r], acc[si][1][r]),
                                      pack2(acc[si][2][r], acc[si][3][r]),
                                      pack2(acc[si][4][r], acc[si][5][r]),
                                      pack2(acc[si][6][r], acc[si][7][r]));
                *(uint4*)(P1 + (size_t)n * 128 + l16 * 8) = pk;
            }
        }
#pragma unroll
    for (int si = 0; si < 2; ++si)
#pragma unroll
        for (int ct = 0; ct < 8; ++ct) acc[si][ct] = (f32x4){0.f, 0.f, 0.f, 0.f};
    mfma4(ah, sWb, l16, q, acc);
#pragma unroll
    for (int si = 0; si < 2; ++si)
#pragma unroll
        for (int r = 0; r < 4; ++r) {
            int n = n0 + (wv * 2 + si) * 16 + q * 4 + r;
            if (n < NN) {
                uint4 pk = make_uint4(pack2(acc[si][0][r], acc[si][1][r]),
                                      pack2(acc[si][2][r], acc[si][3][r]),
                                      pack2(acc[si][4][r], acc[si][5][r]),
                                      pack2(acc[si][6][r], acc[si][7][r]));
                *(uint4*)(P2 + (size_t)n * 128 + l16 * 8) = pk;
            }
        }
}

// ---------------- edge kernel: single-LDS-buffer, 4 blocks/CU ----------------
// R10 structure, LDS halved: sM holds Wt2 (e2) then m (c1 A + reduce); c1's B
// comes straight from global Wt3 (32 KB, L1-resident, uniform across waves).
// LDS ~40 KB -> 4 blocks/CU = 4 waves/SIMD with si=2 sharing intact.
__global__ __launch_bounds__(256, 4) void egcl_edge(
    const float* __restrict__ coord,
    const int* __restrict__ csr_r, const int* __restrict__ csr_c,
    const unsigned short* __restrict__ P1, const unsigned short* __restrict__ P2,
    const unsigned short* __restrict__ Wt2, const unsigned short* __restrict__ Wt3,
    const float* __restrict__ We1,
    const float* __restrict__ be1, const float* __restrict__ be2,
    const float* __restrict__ bc1,
    const float* __restrict__ Wc2, const float* __restrict__ bc2,
    float* __restrict__ m_acc, float* __restrict__ c_sum)
{
    __shared__ __align__(16) unsigned short sM[128 * SST];
    __shared__ float sRad[128], sDif[128][3];
    __shared__ int sSeg[128];
    __shared__ float sWlS[128], sBe1S[128], sBe2[128], sBc1[128], sWc2f[128];

    const int tid = threadIdx.x;
    const int wv = tid >> 6, lane = tid & 63, q = lane >> 4, l16 = lane & 15;
    const int e0 = blockIdx.x * 128;

    int nr[2], nc[2];
#pragma unroll
    for (int si = 0; si < 2; ++si) {
        int e = e0 + (wv * 2 + si) * 16 + l16;
        if (e >= NE) e = NE - 1;
        nr[si] = csr_r[e]; nc[si] = csr_c[e];
    }
    bf16x8 pr[2][4], pc[2][4];
#pragma unroll
    for (int si = 0; si < 2; ++si)
#pragma unroll
        for (int kc = 0; kc < 4; ++kc) {
            pr[si][kc] = *(const bf16x8*)(P1 + (size_t)nr[si] * 128 + kc * 32 + q * 8);
            pc[si][kc] = *(const bf16x8*)(P2 + (size_t)nc[si] * 128 + kc * 32 + q * 8);
        }

    if (tid < 128) {
        // sigma-permute wlast/be1: orig_k(m) = (m%8)*16 + m/8
        int k0 = (tid & 7) * 16 + (tid >> 3);
        sWlS[tid] = We1[256 * 128 + k0]; sBe1S[tid] = be1[k0];
        sBe2[tid] = be2[tid]; sBc1[tid] = bc1[tid]; sWc2f[tid] = Wc2[tid];
        int s = e0 + tid; int sc = (s < NE) ? s : (NE - 1);
        int r = csr_r[sc], c = csr_c[sc];
        sSeg[tid] = (s < NE) ? r : -1;
        float dx = coord[r * 3 + 0] - coord[c * 3 + 0];
        float dy = coord[r * 3 + 1] - coord[c * 3 + 1];
        float dz = coord[r * 3 + 2] - coord[c * 3 + 2];
        float rad = fmaf(dx, dx, fmaf(dy, dy, dz * dz));
        float inv = 1.0f / (sqrtf(rad) + 1e-8f);
        sRad[tid] = rad;
        sDif[tid][0] = dx * inv; sDif[tid][1] = dy * inv; sDif[tid][2] = dz * inv;
    }
    stage128(Wt2, sM, tid);
    const float bc2v = bc2[0];
    BARRIER();   // A: geometry + Wt2(sM) + sigma'd wlast/be1 visible

    // ---- t1 build in registers: silu(P1[r] + P2[c] + rad*wl + be1)
    bf16x8 a[2][4];
#pragma unroll
    for (int si = 0; si < 2; ++si) {
        int row = (wv * 2 + si) * 16 + l16;
        float rad = sRad[row];
#pragma unroll
        for (int kc = 0; kc < 4; ++kc) {
            const float* wl = sWlS + kc * 32 + q * 8;
            const float* be = sBe1S + kc * 32 + q * 8;
            union { bf16x8 v; unsigned int u[4]; } R, C;
            R.v = pr[si][kc]; C.v = pc[si][kc];
            float t[8];
#pragma unroll
            for (int p = 0; p < 4; ++p) {
                t[2 * p]     = bflo(R.u[p]) + bflo(C.u[p]);
                t[2 * p + 1] = bfhi(R.u[p]) + bfhi(C.u[p]);
            }
#pragma unroll
            for (int j = 0; j < 8; ++j)
                t[j] = silu(fmaf(rad, wl[j], t[j] + be[j]));
            union { bf16x8 v; unsigned int u[4]; } O;
            O.u[0] = pack2(t[0], t[1]); O.u[1] = pack2(t[2], t[3]);
            O.u[2] = pack2(t[4], t[5]); O.u[3] = pack2(t[6], t[7]);
            a[si][kc] = O.v;
        }
    }

    // ---- e2: m = silu(t1 @ We2 + be2), B = Wt2 (sM)
    f32x4 acc[2][8];
#pragma unroll
    for (int si = 0; si < 2; ++si)
#pragma unroll
        for (int ct = 0; ct < 8; ++ct) acc[si][ct] = (f32x4){0.f, 0.f, 0.f, 0.f};
    mfma4(a, sM, l16, q, acc);
    uint4 mu[2][4];
#pragma unroll
    for (int si = 0; si < 2; ++si)
#pragma unroll
        for (int r = 0; r < 4; ++r) {
            float v[8];
#pragma unroll
            for (int ct = 0; ct < 8; ++ct) v[ct] = silu(acc[si][ct][r] + sBe2[ct * 16 + l16]);
            mu[si][r] = make_uint4(pack2(v[0], v[1]), pack2(v[2], v[3]),
                                   pack2(v[4], v[5]), pack2(v[6], v[7]));
        }
    BARRIER();   // B: all waves' Wt2 reads done -> sM reusable for m
#pragma unroll
    for (int si = 0; si < 2; ++si)
#pragma unroll
        for (int r = 0; r < 4; ++r) {
            int row = (wv * 2 + si) * 16 + q * 4 + r;
            *(uint4*)(sM + row * SST + l16 * 8) = mu[si][r];
        }
    WAVE_SYNC();  // own-wave m rows visible for own c1 A-reads (wave-private)

    // ---- c1: A = m (own rows, sM), B = Wt3 from global (L1-resident)
#pragma unroll
    for (int si = 0; si < 2; ++si)
#pragma unroll
        for (int ct = 0; ct < 8; ++ct) acc[si][ct] = (f32x4){0.f, 0.f, 0.f, 0.f};
    {
        bf16x8 am[2][4];
#pragma unroll
        for (int si = 0; si < 2; ++si) {
            int row = (wv * 2 + si) * 16 + l16;
#pragma unroll
            for (int kc = 0; kc < 4; ++kc)
                am[si][kc] = *(const bf16x8*)(sM + row * SST + kc * 32 + q * 8);
        }
#pragma unroll
        for (int kc = 0; kc < 4; ++kc)
#pragma unroll
            for (int ct = 0; ct < 8; ++ct) {
                bf16x8 b = *(const bf16x8*)(Wt3 + (size_t)(ct * 16 + l16) * 128 + kc * 32 + q * 8);
                acc[0][ct] = __builtin_amdgcn_mfma_f32_16x16x32_bf16(am[0][kc], b, acc[0][ct], 0, 0, 0);
                acc[1][ct] = __builtin_amdgcn_mfma_f32_16x16x32_bf16(am[1][kc], b, acc[1][ct], 0, 0, 0);
            }
    }
    // c2: silu -> dot Wc2 -> 16-lane reduce -> c_sum atomics
#pragma unroll
    for (int si = 0; si < 2; ++si) {
        float p[4];
#pragma unroll
        for (int r = 0; r < 4; ++r) {
            float s = 0.f;
#pragma unroll
            for (int ct = 0; ct < 8; ++ct) {
                int col = ct * 16 + l16;
                float t = silu(acc[si][ct][r] + sBc1[col]);
                s = fmaf(t, sWc2f[col], s);
            }
            p[r] = s;
        }
#pragma unroll
        for (int m = 1; m < 16; m <<= 1)
#pragma unroll
            for (int r = 0; r < 4; ++r) p[r] += __shfl_xor(p[r], m, 16);
        if (l16 == 0) {
#pragma unroll
            for (int r = 0; r < 4; ++r) {
                int row = (wv * 2 + si) * 16 + q * 4 + r;
                int rn = sSeg[row];
                if (rn >= 0) {
                    float wgt = p[r] + bc2v;
                    atomicAdd(&c_sum[(size_t)rn * 3 + 0], sDif[row][0] * wgt);
                    atomicAdd(&c_sum[(size_t)rn * 3 + 1], sDif[row][1] * wgt);
                    atomicAdd(&c_sum[(size_t)rn * 3 + 2], sDif[row][2] * wgt);
                }
            }
        }
    }
    BARRIER();   // C: all waves' m rows visible for cross-wave reduce

    // ---- segmented m reduction (reads sM), batch-4
    {
        int p = tid & 127, half = tid >> 7;
        int base = half * 64;
        float run = 0.f;
        int cur = sSeg[base];
        bool openL = true;   // current run touches segment start (may continue left)
#pragma unroll 1
        for (int i0 = 0; i0 < 64; i0 += 4) {
            float v[4]; int rr[4];
#pragma unroll
            for (int j = 0; j < 4; ++j) {
                int row = base + i0 + j;
                rr[j] = sSeg[row];
                v[j] = bf2f(sM[row * SST + p]);
            }
#pragma unroll
            for (int j = 0; j < 4; ++j) {
                if (rr[j] != cur) {
                    if (cur >= 0) {
                        float* dst = &m_acc[(size_t)cur * 128 + p];
                        if (openL) atomicAdd(dst, run);
                        else       *dst = run;   // interior run: exclusive writer
                    }
                    run = 0.f; cur = rr[j]; openL = false;
                }
                run += v[j];
            }
        }
        if (cur >= 0) atomicAdd(&m_acc[(size_t)cur * 128 + p], run);  // open at right
    }
}

// ---------------- node kernel: MFMA vel-MLP + node-MLP (R6 unchanged) ----------------
__global__ __launch_bounds__(256, 3) void egcl_node(
    const unsigned short* __restrict__ hb,
    const float* __restrict__ coord,
    const float* __restrict__ vel,
    const unsigned short* __restrict__ Wv1t, const float* __restrict__ bv1,
    const float* __restrict__ Wv2, const float* __restrict__ bv2,
    const unsigned short* __restrict__ Wn1t, const float* __restrict__ bn1,
    const unsigned short* __restrict__ Wn2t, const float* __restrict__ bn2,
    const float* __restrict__ m_acc, const float* __restrict__ c_sum,
    float* __restrict__ out_h, float* __restrict__ out_c)
{
    __shared__ __align__(16) unsigned short sAb[128 * SST];
    __shared__ float sBv1[128], sWv2f[128], sBn1[128], sBn2[128];

    const int tid = threadIdx.x;
    const int wv = tid >> 6, lane = tid & 63, q = lane >> 4, l16 = lane & 15;
    const int n0 = blockIdx.x * 128;
    int nval = NN - n0; if (nval > 128) nval = 128;

    if (tid < 128) {
        sBv1[tid] = bv1[tid]; sWv2f[tid] = Wv2[tid];
        sBn1[tid] = bn1[tid]; sBn2[tid] = bn2[tid];
    }
    const float bv2v = bv2[0];

    bf16x8 ah[2][4], am[2][4];   // am reads sigma-packed m_acc; Wn1t m-half is sigma'd
#pragma unroll
    for (int si = 0; si < 2; ++si) {
        int row = (wv * 2 + si) * 16 + l16;
        int nn = n0 + row; if (nn >= NN) nn = NN - 1;
#pragma unroll
        for (int kc = 0; kc < 4; ++kc) {
            ah[si][kc] = *(const bf16x8*)(hb + (size_t)nn * 128 + kc * 32 + q * 8);
            am[si][kc] = packf8(m_acc + (size_t)nn * 128 + kc * 32 + q * 8);
        }
    }

    BARRIER();   // biases visible

    f32x4 acc[2][8];
    // ---- vel MLP
#pragma unroll
    for (int si = 0; si < 2; ++si)
#pragma unroll
        for (int ct = 0; ct < 8; ++ct) acc[si][ct] = (f32x4){0.f, 0.f, 0.f, 0.f};
#pragma unroll
    for (int kc = 0; kc < 4; ++kc)
#pragma unroll
        for (int ct = 0; ct < 8; ++ct) {
            bf16x8 b = *(const bf16x8*)(Wv1t + (size_t)(ct * 16 + l16) * 128 + kc * 32 + q * 8);
            acc[0][ct] = __builtin_amdgcn_mfma_f32_16x16x32_bf16(ah[0][kc], b, acc[0][ct], 0, 0, 0);
            acc[1][ct] = __builtin_amdgcn_mfma_f32_16x16x32_bf16(ah[1][kc], b, acc[1][ct], 0, 0, 0);
        }
#pragma unroll
    for (int si = 0; si < 2; ++si) {
        float p[4];
#pragma unroll
        for (int r = 0; r < 4; ++r) {
            float s = 0.f;
#pragma unroll
            for (int ct = 0; ct < 8; ++ct) {
                int col = ct * 16 + l16;
                float t = silu(acc[si][ct][r] + sBv1[col]);
                s = fmaf(t, sWv2f[col], s);
            }
            p[r] = s;
        }
#pragma unroll
        for (int m = 1; m < 16; m <<= 1)
#pragma unroll
            for (int r = 0; r < 4; ++r) p[r] += __shfl_xor(p[r], m, 16);
        if (l16 == 0) {
#pragma unroll
            for (int r = 0; r < 4; ++r) {
                int row = (wv * 2 + si) * 16 + q * 4 + r;
                int n = n0 + row;
                if (row < nval) {
                    float vw = p[r] + bv2v;
#pragma unroll
                    for (int d = 0; d < 3; ++d) {
                        float cv = coord[(size_t)n * 3 + d] + c_sum[(size_t)n * 3 + d]
                                 + vel[(size_t)n * 3 + d] * vw;
                        out_c[(size_t)n * 3 + d] = cv;
                    }
                }
            }
        }
    }

    // ---- n1: K=256 on [h | m_i]
#pragma unroll
    for (int si = 0; si < 2; ++si)
#pragma unroll
        for (int ct = 0; ct < 8; ++ct) acc[si][ct] = (f32x4){0.f, 0.f, 0.f, 0.f};
#pragma unroll
    for (int kc = 0; kc < 8; ++kc)
#pragma unroll
        for (int ct = 0; ct < 8; ++ct) {
            bf16x8 b = *(const bf16x8*)(Wn1t + (size_t)(ct * 16 + l16) * 256 + kc * 32 + q * 8);
            bf16x8 a0 = (kc < 4) ? ah[0][kc & 3] : am[0][kc & 3];
            bf16x8 a1 = (kc < 4) ? ah[1][kc & 3] : am[1][kc & 3];
            acc[0][ct] = __builtin_amdgcn_mfma_f32_16x16x32_bf16(a0, b, acc[0][ct], 0, 0, 0);
            acc[1][ct] = __builtin_amdgcn_mfma_f32_16x16x32_bf16(a1, b, acc[1][ct], 0, 0, 0);
        }
#pragma unroll
    for (int si = 0; si < 2; ++si)
#pragma unroll
        for (int r = 0; r < 4; ++r) {
            int row = (wv * 2 + si) * 16 + q * 4 + r;
            float v[8];
#pragma unroll
            for (int ct = 0; ct < 8; ++ct) v[ct] = silu(acc[si][ct][r] + sBn1[ct * 16 + l16]);
            uint4 pk = make_uint4(pack2(v[0], v[1]), pack2(v[2], v[3]),
                                  pack2(v[4], v[5]), pack2(v[6], v[7]));
            *(uint4*)(sAb + row * SST + l16 * 8) = pk;
        }

    BARRIER();   // t1 visible

    // ---- n2
#pragma unroll
    for (int si = 0; si < 2; ++si)
#pragma unroll
        for (int ct = 0; ct < 8; ++ct) acc[si][ct] = (f32x4){0.f, 0.f, 0.f, 0.f};
    {
        bf16x8 a[2][4];
#pragma unroll
        for (int si = 0; si < 2; ++si) {
            int row = (wv * 2 + si) * 16 + l16;
#pragma unroll
            for (int kc = 0; kc < 4; ++kc)
                a[si][kc] = *(const bf16x8*)(sAb + row * SST + kc * 32 + q * 8);
        }
#pragma unroll
        for (int kc = 0; kc < 4; ++kc)
#pragma unroll
            for (int ct = 0; ct < 8; ++ct) {
                bf16x8 b = *(const bf16x8*)(Wn2t + (size_t)(ct * 16 + l16) * 128 + kc * 32 + q * 8);
                acc[0][ct] = __builtin_amdgcn_mfma_f32_16x16x32_bf16(a[0][kc], b, acc[0][ct], 0, 0, 0);
                acc[1][ct] = __builtin_amdgcn_mfma_f32_16x16x32_bf16(a[1][kc], b, acc[1][ct], 0, 0, 0);
            }
    }
#pragma unroll
    for (int si = 0; si < 2; ++si)
#pragma unroll
        for (int r = 0; r < 4; ++r) {
            int row = (wv * 2 + si) * 16 + q * 4 + r;
            if (row < nval) {
                float* orow = out_h + (size_t)(n0 + row) * 128;
#pragma unroll
                for (int ct = 0; ct < 8; ++ct)
                    orow[ct * 16 + l16] = acc[si][ct][r] + sBn2[ct * 16 + l16];
            }
        }
}

extern "C" void kernel_launch(void* const* d_in, const int* in_sizes, int n_in,
                              void* d_out, int out_size, void* d_ws, size_t ws_size,
                              hipStream_t stream) {
    const float* h     = (const float*)d_in[0];
    const float* coord = (const float*)d_in[1];
    const float* vel   = (const float*)d_in[2];
    const int*   eidx  = (const int*)d_in[3];
    const float* We1 = (const float*)d_in[4];
    const float* be1 = (const float*)d_in[5];
    const float* We2 = (const float*)d_in[6];
    const float* be2 = (const float*)d_in[7];
    const float* Wc1 = (const float*)d_in[8];
    const float* bc1 = (const float*)d_in[9];
    const float* Wc2 = (const float*)d_in[10];
    const float* bc2 = (const float*)d_in[11];
    const float* Wv1 = (const float*)d_in[12];
    const float* bv1 = (const float*)d_in[13];
    const float* Wv2 = (const float*)d_in[14];
    const float* bv2 = (const float*)d_in[15];
    const float* Wn1 = (const float*)d_in[16];
    const float* bn1 = (const float*)d_in[17];
    const float* Wn2 = (const float*)d_in[18];
    const float* bn2 = (const float*)d_in[19];

    char* ws = (char*)d_ws;
    float* m_acc = (float*)ws;                                  // [NN][128] f32 sigma-packed
    float* c_sum = (float*)(ws + 25600000);                     // [NN][3] f32
    unsigned short* hb   = (unsigned short*)(ws + 26200064);    // [NN][128] bf16
    unsigned short* Wt1  = (unsigned short*)(ws + 39000064);
    unsigned short* Wt2  = (unsigned short*)(ws + 39065600);
    unsigned short* Wt3  = (unsigned short*)(ws + 39098368);
    unsigned short* Wv1t = (unsigned short*)(ws + 39131136);
    unsigned short* Wn1t = (unsigned short*)(ws + 39163904);
    unsigned short* Wn2t = (unsigned short*)(ws + 39229440);
    int* deg    = (int*)(ws + 39262208);                        // [NN]
    int* cursor = (int*)(ws + 39462208);                        // [NN]
    int* rowptr = (int*)(ws + 39662208);                        // [NN+1]
    int* bsum   = (int*)(ws + 39862272);                        // [256]
    int* csr_r  = (int*)(ws + 39863296);                        // [NE]
    int* csr_c  = (int*)(ws + 41863296);                        // [NE]
    unsigned short* P1 = (unsigned short*)(ws + 43863296);      // [NN][128] bf16 sigma
    unsigned short* P2 = (unsigned short*)(ws + 56663296);      // [NN][128] bf16 sigma

    hipMemsetAsync(ws, 0, 26200000, stream);          // m_acc + c_sum
    hipMemsetAsync(ws + 39262208, 0, 400000, stream); // deg + cursor

    prep_h<<<6250, 256, 0, stream>>>(h, hb);
    prep_w<<<512, 256, 0, stream>>>(We1, We2, Wc1, Wv1, Wn1, Wn2,
                                    Wt1, Wt2, Wt3, Wv1t, Wn1t, Wn2t);
    prep_P<<<(NN + 127) / 128, 256, 0, stream>>>(hb, Wt1, P1, P2);

    csr_count<<<1954, 256, 0, stream>>>(eidx, deg);
    scan_a<<<196, 256, 0, stream>>>(deg, bsum);
    scan_b<<<1, 256, 0, stream>>>(bsum);
    scan_c<<<196, 256, 0, stream>>>(deg, bsum, rowptr);
    csr_fill<<<1954, 256, 0, stream>>>(eidx, rowptr, cursor, csr_r, csr_c);

    egcl_edge<<<NEB, 256, 0, stream>>>(
        coord, csr_r, csr_c, P1, P2, Wt2, Wt3,
        We1, be1, be2, bc1, Wc2, bc2, m_acc, c_sum);

    float* out_h = (float*)d_out;
    float* out_c = out_h + (size_t)NN * 128;
    egcl_node<<<(NN + 127) / 128, 256, 0, stream>>>(
        hb, coord, vel, Wv1t, bv1, Wv2, bv2, Wn1t, bn1, Wn2t, bn2,
        m_acc, c_sum, out_h, out_c);
}

// Round 12
// 392.162 us; speedup vs baseline: 1.0234x; 1.0234x over previous
//
#include <hip/hip_runtime.h>
#include <stdint.h>

#define NN 50000
#define NE 500000
#define NEB ((NE + 127) / 128)
#define SST 136   // LDS row stride in shorts (272 B -> 2-way banks on b128 reads)

#define BARRIER() asm volatile("s_waitcnt lgkmcnt(0)\n\ts_barrier" ::: "memory")
#define WAVE_SYNC() asm volatile("s_waitcnt lgkmcnt(0)" ::: "memory")

typedef __attribute__((ext_vector_type(8))) short bf16x8;
typedef __attribute__((ext_vector_type(4))) float f32x4;

// fast silu: x * v_rcp(1+e^-x). 1-instr rcp vs ~8-instr IEEE div; +-1 ulp. (R6)
__device__ __forceinline__ float silu(float x) {
    float e = __expf(-x);
    return x * __builtin_amdgcn_rcpf(1.0f + e);
}
__device__ __forceinline__ float bf2f(unsigned short s) {
    union { unsigned int u; float f; } v; v.u = ((unsigned int)s) << 16; return v.f;
}
__device__ __forceinline__ float bflo(unsigned int u) {   // low bf16 of packed pair
    union { unsigned int u; float f; } v; v.u = u << 16; return v.f;
}
__device__ __forceinline__ float bfhi(unsigned int u) {   // high bf16 of packed pair
    union { unsigned int u; float f; } v; v.u = u & 0xffff0000u; return v.f;
}
__device__ __forceinline__ unsigned short f2bf(float f) {   // RNE (prep only)
    union { float f; unsigned int u; } v; v.f = f;
    return (unsigned short)((v.u + 0x7fffu + ((v.u >> 16) & 1u)) >> 16);
}
// HW packed f32->bf16 (RNE): 1 instr
__device__ __forceinline__ unsigned int pack2(float a, float b) {
    unsigned int r;
    asm("v_cvt_pk_bf16_f32 %0, %1, %2" : "=v"(r) : "v"(a), "v"(b));
    return r;
}
__device__ __forceinline__ bf16x8 packf8(const float* p) {
    float4 f0 = *(const float4*)p; float4 f1 = *(const float4*)(p + 4);
    union { bf16x8 v; unsigned int u[4]; } o;
    o.u[0] = pack2(f0.x, f0.y); o.u[1] = pack2(f0.z, f0.w);
    o.u[2] = pack2(f1.x, f1.y); o.u[3] = pack2(f1.z, f1.w);
    return o.v;
}

// ---------------- prep ----------------
__global__ void prep_h(const float* __restrict__ h, unsigned short* __restrict__ hb) {
    int i = blockIdx.x * 256 + threadIdx.x;
    if (i < NN * 128 / 4) {
        float4 v = ((const float4*)h)[i];
        uint2 o; o.x = pack2(v.x, v.y); o.y = pack2(v.z, v.w);
        ((uint2*)hb)[i] = o;
    }
}

// B^T layouts. sigma(col) = (col%16)*8 + col/16 ; orig_k(ks) = (ks%8)*16 + ks/8
__global__ void prep_w(const float* __restrict__ We1, const float* __restrict__ We2,
                       const float* __restrict__ Wc1, const float* __restrict__ Wv1,
                       const float* __restrict__ Wn1, const float* __restrict__ Wn2,
                       unsigned short* __restrict__ Wt1, unsigned short* __restrict__ Wt2,
                       unsigned short* __restrict__ Wt3, unsigned short* __restrict__ Wv1t,
                       unsigned short* __restrict__ Wn1t, unsigned short* __restrict__ Wn2t) {
    int i = blockIdx.x * 256 + threadIdx.x;
    if (i < 32768) {                                    // Wt1 [128][256] natural
        int j = i >> 8, k = i & 255;
        Wt1[i] = f2bf(We1[k * 128 + j]);
    } else if (i < 49152) {                             // Wt2 [128][128] sigma
        int t = i - 32768; int j = t >> 7, ks = t & 127;
        int k0 = (ks & 7) * 16 + (ks >> 3);
        Wt2[t] = f2bf(We2[k0 * 128 + j]);
    } else if (i < 65536) {                             // Wt3 [128][128] sigma
        int t = i - 49152; int j = t >> 7, ks = t & 127;
        int k0 = (ks & 7) * 16 + (ks >> 3);
        Wt3[t] = f2bf(Wc1[k0 * 128 + j]);
    } else if (i < 81920) {                             // Wv1t [128][128] natural
        int t = i - 65536; int j = t >> 7, k = t & 127;
        Wv1t[t] = f2bf(Wv1[k * 128 + j]);
    } else if (i < 114688) {                            // Wn1t [128][256]: h natural, m sigma
        int t = i - 81920; int j = t >> 8, k = t & 255;
        int ksrc;
        if (k < 128) ksrc = k;
        else { int ks = k - 128; ksrc = 128 + (ks & 7) * 16 + (ks >> 3); }
        Wn1t[t] = f2bf(Wn1[ksrc * 128 + j]);
    } else if (i < 131072) {                            // Wn2t [128][128] sigma
        int t = i - 114688; int j = t >> 7, ks = t & 127;
        int k0 = (ks & 7) * 16 + (ks >> 3);
        Wn2t[t] = f2bf(Wn2[k0 * 128 + j]);
    }
}

// ---------------- CSR build ----------------
__global__ void csr_count(const int* __restrict__ eidx, int* __restrict__ deg) {
    int e = blockIdx.x * 256 + threadIdx.x;
    if (e < NE) atomicAdd(&deg[eidx[e]], 1);
}

__global__ void scan_a(const int* __restrict__ deg, int* __restrict__ bsum) {
    __shared__ int s[256];
    int t = threadIdx.x, idx = blockIdx.x * 256 + t;
    s[t] = (idx < NN) ? deg[idx] : 0;
    __syncthreads();
    for (int off = 128; off > 0; off >>= 1) {
        if (t < off) s[t] += s[t + off];
        __syncthreads();
    }
    if (t == 0) bsum[blockIdx.x] = s[0];
}

__global__ void scan_b(int* __restrict__ bsum) {   // exclusive scan, 196 values
    __shared__ int s[256];
    int t = threadIdx.x;
    int v = (t < 196) ? bsum[t] : 0;
    s[t] = v;
    __syncthreads();
    for (int off = 1; off < 256; off <<= 1) {
        int x = (t >= off) ? s[t - off] : 0;
        __syncthreads();
        s[t] += x;
        __syncthreads();
    }
    if (t < 196) bsum[t] = s[t] - v;
}

__global__ void scan_c(const int* __restrict__ deg, const int* __restrict__ bsum,
                       int* __restrict__ rowptr) {
    __shared__ int s[256];
    int t = threadIdx.x, idx = blockIdx.x * 256 + t;
    int v = (idx < NN) ? deg[idx] : 0;
    s[t] = v;
    __syncthreads();
    for (int off = 1; off < 256; off <<= 1) {
        int x = (t >= off) ? s[t - off] : 0;
        __syncthreads();
        s[t] += x;
        __syncthreads();
    }
    if (idx < NN) rowptr[idx] = bsum[blockIdx.x] + s[t] - v;
    if (idx == 0) rowptr[NN] = NE;
}

__global__ void csr_fill(const int* __restrict__ eidx, const int* __restrict__ rowptr,
                         int* __restrict__ cursor,
                         int* __restrict__ csr_r, int* __restrict__ csr_c) {
    int e = blockIdx.x * 256 + threadIdx.x;
    if (e < NE) {
        int r = eidx[e], c = eidx[NE + e];
        int slot = rowptr[r] + atomicAdd(&cursor[r], 1);
        csr_r[slot] = r; csr_c[slot] = c;
    }
}

// ---------------- helpers (256-thread staging) ----------------
__device__ __forceinline__ void stage256(const unsigned short* __restrict__ W, int halfk,
                                         unsigned short* sW, int tid) {
#pragma unroll
    for (int t = 0; t < 8; ++t) {
        int idx = tid + t * 256; int j = idx >> 4, g = idx & 15;
        *(uint4*)(sW + j * SST + g * 8) = *(const uint4*)(W + (size_t)j * 256 + halfk * 128 + g * 8);
    }
}
__device__ __forceinline__ void stage128(const unsigned short* __restrict__ W,
                                         unsigned short* sW, int tid) {
#pragma unroll
    for (int t = 0; t < 8; ++t) {
        int idx = tid + t * 256; int j = idx >> 4, g = idx & 15;
        *(uint4*)(sW + j * SST + g * 8) = *(const uint4*)(W + (size_t)j * 128 + g * 8);
    }
}
__device__ __forceinline__ void mfma4(const bf16x8 a[2][4], const unsigned short* sW,
                                      int l16, int q, f32x4 acc[2][8]) {
#pragma unroll
    for (int kc = 0; kc < 4; ++kc)
#pragma unroll
        for (int ct = 0; ct < 8; ++ct) {
            bf16x8 b = *(const bf16x8*)(sW + (ct * 16 + l16) * SST + kc * 32 + q * 8);
            acc[0][ct] = __builtin_amdgcn_mfma_f32_16x16x32_bf16(a[0][kc], b, acc[0][ct], 0, 0, 0);
            acc[1][ct] = __builtin_amdgcn_mfma_f32_16x16x32_bf16(a[1][kc], b, acc[1][ct], 0, 0, 0);
        }
}

// ---------------- prep_P: per-NODE halves of e1 ----------------
// P1[n] = h[n] @ We1[0:128], P2[n] = h[n] @ We1[128:256]; stored bf16
// SIGMA-packed so the edge kernel gathers them directly as e2 A-fragments.
__global__ __launch_bounds__(256, 2) void prep_P(
    const unsigned short* __restrict__ hb,
    const unsigned short* __restrict__ Wt1,
    unsigned short* __restrict__ P1, unsigned short* __restrict__ P2)
{
    __shared__ __align__(16) unsigned short sWa[128 * SST];
    __shared__ __align__(16) unsigned short sWb[128 * SST];
    const int tid = threadIdx.x;
    const int wv = tid >> 6, lane = tid & 63, q = lane >> 4, l16 = lane & 15;
    const int n0 = blockIdx.x * 128;

    stage256(Wt1, 0, sWa, tid);
    stage256(Wt1, 1, sWb, tid);
    bf16x8 ah[2][4];
#pragma unroll
    for (int si = 0; si < 2; ++si) {
        int nn = n0 + (wv * 2 + si) * 16 + l16; if (nn >= NN) nn = NN - 1;
#pragma unroll
        for (int kc = 0; kc < 4; ++kc)
            ah[si][kc] = *(const bf16x8*)(hb + (size_t)nn * 128 + kc * 32 + q * 8);
    }
    BARRIER();

    f32x4 acc[2][8];
#pragma unroll
    for (int si = 0; si < 2; ++si)
#pragma unroll
        for (int ct = 0; ct < 8; ++ct) acc[si][ct] = (f32x4){0.f, 0.f, 0.f, 0.f};
    mfma4(ah, sWa, l16, q, acc);
#pragma unroll
    for (int si = 0; si < 2; ++si)
#pragma unroll
        for (int r = 0; r < 4; ++r) {
            int n = n0 + (wv * 2 + si) * 16 + q * 4 + r;
            if (n < NN) {
                uint4 pk = make_uint4(pack2(acc[si][0][r], acc[si][1][r]),
                                      pack2(acc[si][2][r], acc[si][3][r]),
                                      pack2(acc[si][4][r], acc[si][5][r]),
                                      pack2(acc[si][6][r], acc[si][7][r]));
                *(uint4*)(P1 + (size_t)n * 128 + l16 * 8) = pk;
            }
        }
#pragma unroll
    for (int si = 0; si < 2; ++si)
#pragma unroll
        for (int ct = 0; ct < 8; ++ct) acc[si][ct] = (f32x4){0.f, 0.f, 0.f, 0.f};
    mfma4(ah, sWb, l16, q, acc);
#pragma unroll
    for (int si = 0; si < 2; ++si)
#pragma unroll
        for (int r = 0; r < 4; ++r) {
            int n = n0 + (wv * 2 + si) * 16 + q * 4 + r;
            if (n < NN) {
                uint4 pk = make_uint4(pack2(acc[si][0][r], acc[si][1][r]),
                                      pack2(acc[si][2][r], acc[si][3][r]),
                                      pack2(acc[si][4][r], acc[si][5][r]),
                                      pack2(acc[si][6][r], acc[si][7][r]));
                *(uint4*)(P2 + (size_t)n * 128 + l16 * 8) = pk;
            }
        }
}

// ---------------- edge kernel: e1 eliminated (P-gather), 2 GEMM stages ------
// t1 built in registers from P1[r]+P2[c]+rad*wlast+be1 (wlast/be1 sigma-
// permuted so k-order matches sigma-staged Wt2). 3 barriers.
// sM: Wt2 -> (after B) m; sB3: Wt3. 2 blocks/CU (proven optimum; occupancy
// experiments R4/R8/R9/R11 all null-or-negative on this kernel family).
__global__ __launch_bounds__(256, 2) void egcl_edge(
    const float* __restrict__ coord,
    const int* __restrict__ csr_r, const int* __restrict__ csr_c,
    const unsigned short* __restrict__ P1, const unsigned short* __restrict__ P2,
    const unsigned short* __restrict__ Wt2, const unsigned short* __restrict__ Wt3,
    const float* __restrict__ We1,
    const float* __restrict__ be1, const float* __restrict__ be2,
    const float* __restrict__ bc1,
    const float* __restrict__ Wc2, const float* __restrict__ bc2,
    float* __restrict__ m_acc, float* __restrict__ c_sum)
{
    __shared__ __align__(16) unsigned short sM[128 * SST];
    __shared__ __align__(16) unsigned short sB3[128 * SST];
    __shared__ float sRad[128], sDif[128][3];
    __shared__ int sSeg[128];
    __shared__ float sWlS[128], sBe1S[128], sBe2[128], sBc1[128], sWc2f[128];

    const int tid = threadIdx.x;
    const int wv = tid >> 6, lane = tid & 63, q = lane >> 4, l16 = lane & 15;
    const int e0 = blockIdx.x * 128;

    int nr[2], nc[2];
#pragma unroll
    for (int si = 0; si < 2; ++si) {
        int e = e0 + (wv * 2 + si) * 16 + l16;
        if (e >= NE) e = NE - 1;
        nr[si] = csr_r[e]; nc[si] = csr_c[e];
    }
    // gather P fragments early (replaces h-gather 1:1)
    bf16x8 pr[2][4], pc[2][4];
#pragma unroll
    for (int si = 0; si < 2; ++si)
#pragma unroll
        for (int kc = 0; kc < 4; ++kc) {
            pr[si][kc] = *(const bf16x8*)(P1 + (size_t)nr[si] * 128 + kc * 32 + q * 8);
            pc[si][kc] = *(const bf16x8*)(P2 + (size_t)nc[si] * 128 + kc * 32 + q * 8);
        }

    if (tid < 128) {
        // sigma-permute wlast/be1: orig_k(m) = (m%8)*16 + m/8
        int k0 = (tid & 7) * 16 + (tid >> 3);
        sWlS[tid] = We1[256 * 128 + k0]; sBe1S[tid] = be1[k0];
        sBe2[tid] = be2[tid]; sBc1[tid] = bc1[tid]; sWc2f[tid] = Wc2[tid];
        int s = e0 + tid; int sc = (s < NE) ? s : (NE - 1);
        int r = csr_r[sc], c = csr_c[sc];
        sSeg[tid] = (s < NE) ? r : -1;
        float dx = coord[r * 3 + 0] - coord[c * 3 + 0];
        float dy = coord[r * 3 + 1] - coord[c * 3 + 1];
        float dz = coord[r * 3 + 2] - coord[c * 3 + 2];
        float rad = fmaf(dx, dx, fmaf(dy, dy, dz * dz));
        float inv = 1.0f / (sqrtf(rad) + 1e-8f);
        sRad[tid] = rad;
        sDif[tid][0] = dx * inv; sDif[tid][1] = dy * inv; sDif[tid][2] = dz * inv;
    }
    stage128(Wt2, sM, tid);
    stage128(Wt3, sB3, tid);
    const float bc2v = bc2[0];
    BARRIER();   // A: geometry + Wt2(sM) + Wt3(sB3) + sigma'd wlast/be1 visible

    // ---- t1 build in registers: silu(P1[r] + P2[c] + rad*wl + be1)
    bf16x8 a[2][4];
#pragma unroll
    for (int si = 0; si < 2; ++si) {
        int row = (wv * 2 + si) * 16 + l16;
        float rad = sRad[row];
#pragma unroll
        for (int kc = 0; kc < 4; ++kc) {
            const float* wl = sWlS + kc * 32 + q * 8;
            const float* be = sBe1S + kc * 32 + q * 8;
            union { bf16x8 v; unsigned int u[4]; } R, C;
            R.v = pr[si][kc]; C.v = pc[si][kc];
            float t[8];
#pragma unroll
            for (int p = 0; p < 4; ++p) {
                t[2 * p]     = bflo(R.u[p]) + bflo(C.u[p]);
                t[2 * p + 1] = bfhi(R.u[p]) + bfhi(C.u[p]);
            }
#pragma unroll
            for (int j = 0; j < 8; ++j)
                t[j] = silu(fmaf(rad, wl[j], t[j] + be[j]));
            union { bf16x8 v; unsigned int u[4]; } O;
            O.u[0] = pack2(t[0], t[1]); O.u[1] = pack2(t[2], t[3]);
            O.u[2] = pack2(t[4], t[5]); O.u[3] = pack2(t[6], t[7]);
            a[si][kc] = O.v;
        }
    }

    // ---- e2: m = silu(t1 @ We2 + be2), B = Wt2 (sM)
    f32x4 acc[2][8];
#pragma unroll
    for (int si = 0; si < 2; ++si)
#pragma unroll
        for (int ct = 0; ct < 8; ++ct) acc[si][ct] = (f32x4){0.f, 0.f, 0.f, 0.f};
    mfma4(a, sM, l16, q, acc);
    uint4 mu[2][4];
#pragma unroll
    for (int si = 0; si < 2; ++si)
#pragma unroll
        for (int r = 0; r < 4; ++r) {
            float v[8];
#pragma unroll
            for (int ct = 0; ct < 8; ++ct) v[ct] = silu(acc[si][ct][r] + sBe2[ct * 16 + l16]);
            mu[si][r] = make_uint4(pack2(v[0], v[1]), pack2(v[2], v[3]),
                                   pack2(v[4], v[5]), pack2(v[6], v[7]));
        }
    BARRIER();   // B: all waves' Wt2 reads done -> sM reusable for m
#pragma unroll
    for (int si = 0; si < 2; ++si)
#pragma unroll
        for (int r = 0; r < 4; ++r) {
            int row = (wv * 2 + si) * 16 + q * 4 + r;
            *(uint4*)(sM + row * SST + l16 * 8) = mu[si][r];
        }
    WAVE_SYNC();  // own-wave m rows visible for own c1 A-reads (wave-private)

    // ---- c1: A = m (own rows, sM), B = Wt3 (sB3)
#pragma unroll
    for (int si = 0; si < 2; ++si)
#pragma unroll
        for (int ct = 0; ct < 8; ++ct) acc[si][ct] = (f32x4){0.f, 0.f, 0.f, 0.f};
    {
        bf16x8 am[2][4];
#pragma unroll
        for (int si = 0; si < 2; ++si) {
            int row = (wv * 2 + si) * 16 + l16;
#pragma unroll
            for (int kc = 0; kc < 4; ++kc)
                am[si][kc] = *(const bf16x8*)(sM + row * SST + kc * 32 + q * 8);
        }
        mfma4(am, sB3, l16, q, acc);
    }
    // c2: silu -> dot Wc2 -> 16-lane reduce -> c_sum atomics
#pragma unroll
    for (int si = 0; si < 2; ++si) {
        float p[4];
#pragma unroll
        for (int r = 0; r < 4; ++r) {
            float s = 0.f;
#pragma unroll
            for (int ct = 0; ct < 8; ++ct) {
                int col = ct * 16 + l16;
                float t = silu(acc[si][ct][r] + sBc1[col]);
                s = fmaf(t, sWc2f[col], s);
            }
            p[r] = s;
        }
#pragma unroll
        for (int m = 1; m < 16; m <<= 1)
#pragma unroll
            for (int r = 0; r < 4; ++r) p[r] += __shfl_xor(p[r], m, 16);
        if (l16 == 0) {
#pragma unroll
            for (int r = 0; r < 4; ++r) {
                int row = (wv * 2 + si) * 16 + q * 4 + r;
                int rn = sSeg[row];
                if (rn >= 0) {
                    float wgt = p[r] + bc2v;
                    atomicAdd(&c_sum[(size_t)rn * 3 + 0], sDif[row][0] * wgt);
                    atomicAdd(&c_sum[(size_t)rn * 3 + 1], sDif[row][1] * wgt);
                    atomicAdd(&c_sum[(size_t)rn * 3 + 2], sDif[row][2] * wgt);
                }
            }
        }
    }
    BARRIER();   // C: all waves' m rows visible for cross-wave reduce

    // ---- segmented m reduction (reads sM), batch-4
    {
        int p = tid & 127, half = tid >> 7;
        int base = half * 64;
        float run = 0.f;
        int cur = sSeg[base];
        bool openL = true;   // current run touches segment start (may continue left)
#pragma unroll 1
        for (int i0 = 0; i0 < 64; i0 += 4) {
            float v[4]; int rr[4];
#pragma unroll
            for (int j = 0; j < 4; ++j) {
                int row = base + i0 + j;
                rr[j] = sSeg[row];
                v[j] = bf2f(sM[row * SST + p]);
            }
#pragma unroll
            for (int j = 0; j < 4; ++j) {
                if (rr[j] != cur) {
                    if (cur >= 0) {
                        float* dst = &m_acc[(size_t)cur * 128 + p];
                        if (openL) atomicAdd(dst, run);
                        else       *dst = run;   // interior run: exclusive writer
                    }
                    run = 0.f; cur = rr[j]; openL = false;
                }
                run += v[j];
            }
        }
        if (cur >= 0) atomicAdd(&m_acc[(size_t)cur * 128 + p], run);  // open at right
    }
}

// ---------------- node kernel: MFMA vel-MLP + node-MLP (R6 unchanged) ----------------
__global__ __launch_bounds__(256, 3) void egcl_node(
    const unsigned short* __restrict__ hb,
    const float* __restrict__ coord,
    const float* __restrict__ vel,
    const unsigned short* __restrict__ Wv1t, const float* __restrict__ bv1,
    const float* __restrict__ Wv2, const float* __restrict__ bv2,
    const unsigned short* __restrict__ Wn1t, const float* __restrict__ bn1,
    const unsigned short* __restrict__ Wn2t, const float* __restrict__ bn2,
    const float* __restrict__ m_acc, const float* __restrict__ c_sum,
    float* __restrict__ out_h, float* __restrict__ out_c)
{
    __shared__ __align__(16) unsigned short sAb[128 * SST];
    __shared__ float sBv1[128], sWv2f[128], sBn1[128], sBn2[128];

    const int tid = threadIdx.x;
    const int wv = tid >> 6, lane = tid & 63, q = lane >> 4, l16 = lane & 15;
    const int n0 = blockIdx.x * 128;
    int nval = NN - n0; if (nval > 128) nval = 128;

    if (tid < 128) {
        sBv1[tid] = bv1[tid]; sWv2f[tid] = Wv2[tid];
        sBn1[tid] = bn1[tid]; sBn2[tid] = bn2[tid];
    }
    const float bv2v = bv2[0];

    bf16x8 ah[2][4], am[2][4];   // am reads sigma-packed m_acc; Wn1t m-half is sigma'd
#pragma unroll
    for (int si = 0; si < 2; ++si) {
        int row = (wv * 2 + si) * 16 + l16;
        int nn = n0 + row; if (nn >= NN) nn = NN - 1;
#pragma unroll
        for (int kc = 0; kc < 4; ++kc) {
            ah[si][kc] = *(const bf16x8*)(hb + (size_t)nn * 128 + kc * 32 + q * 8);
            am[si][kc] = packf8(m_acc + (size_t)nn * 128 + kc * 32 + q * 8);
        }
    }

    BARRIER();   // biases visible

    f32x4 acc[2][8];
    // ---- vel MLP
#pragma unroll
    for (int si = 0; si < 2; ++si)
#pragma unroll
        for (int ct = 0; ct < 8; ++ct) acc[si][ct] = (f32x4){0.f, 0.f, 0.f, 0.f};
#pragma unroll
    for (int kc = 0; kc < 4; ++kc)
#pragma unroll
        for (int ct = 0; ct < 8; ++ct) {
            bf16x8 b = *(const bf16x8*)(Wv1t + (size_t)(ct * 16 + l16) * 128 + kc * 32 + q * 8);
            acc[0][ct] = __builtin_amdgcn_mfma_f32_16x16x32_bf16(ah[0][kc], b, acc[0][ct], 0, 0, 0);
            acc[1][ct] = __builtin_amdgcn_mfma_f32_16x16x32_bf16(ah[1][kc], b, acc[1][ct], 0, 0, 0);
        }
#pragma unroll
    for (int si = 0; si < 2; ++si) {
        float p[4];
#pragma unroll
        for (int r = 0; r < 4; ++r) {
            float s = 0.f;
#pragma unroll
            for (int ct = 0; ct < 8; ++ct) {
                int col = ct * 16 + l16;
                float t = silu(acc[si][ct][r] + sBv1[col]);
                s = fmaf(t, sWv2f[col], s);
            }
            p[r] = s;
        }
#pragma unroll
        for (int m = 1; m < 16; m <<= 1)
#pragma unroll
            for (int r = 0; r < 4; ++r) p[r] += __shfl_xor(p[r], m, 16);
        if (l16 == 0) {
#pragma unroll
            for (int r = 0; r < 4; ++r) {
                int row = (wv * 2 + si) * 16 + q * 4 + r;
                int n = n0 + row;
                if (row < nval) {
                    float vw = p[r] + bv2v;
#pragma unroll
                    for (int d = 0; d < 3; ++d) {
                        float cv = coord[(size_t)n * 3 + d] + c_sum[(size_t)n * 3 + d]
                                 + vel[(size_t)n * 3 + d] * vw;
                        out_c[(size_t)n * 3 + d] = cv;
                    }
                }
            }
        }
    }

    // ---- n1: K=256 on [h | m_i]
#pragma unroll
    for (int si = 0; si < 2; ++si)
#pragma unroll
        for (int ct = 0; ct < 8; ++ct) acc[si][ct] = (f32x4){0.f, 0.f, 0.f, 0.f};
#pragma unroll
    for (int kc = 0; kc < 8; ++kc)
#pragma unroll
        for (int ct = 0; ct < 8; ++ct) {
            bf16x8 b = *(const bf16x8*)(Wn1t + (size_t)(ct * 16 + l16) * 256 + kc * 32 + q * 8);
            bf16x8 a0 = (kc < 4) ? ah[0][kc & 3] : am[0][kc & 3];
            bf16x8 a1 = (kc < 4) ? ah[1][kc & 3] : am[1][kc & 3];
            acc[0][ct] = __builtin_amdgcn_mfma_f32_16x16x32_bf16(a0, b, acc[0][ct], 0, 0, 0);
            acc[1][ct] = __builtin_amdgcn_mfma_f32_16x16x32_bf16(a1, b, acc[1][ct], 0, 0, 0);
        }
#pragma unroll
    for (int si = 0; si < 2; ++si)
#pragma unroll
        for (int r = 0; r < 4; ++r) {
            int row = (wv * 2 + si) * 16 + q * 4 + r;
            float v[8];
#pragma unroll
            for (int ct = 0; ct < 8; ++ct) v[ct] = silu(acc[si][ct][r] + sBn1[ct * 16 + l16]);
            uint4 pk = make_uint4(pack2(v[0], v[1]), pack2(v[2], v[3]),
                                  pack2(v[4], v[5]), pack2(v[6], v[7]));
            *(uint4*)(sAb + row * SST + l16 * 8) = pk;
        }

    BARRIER();   // t1 visible

    // ---- n2
#pragma unroll
    for (int si = 0; si < 2; ++si)
#pragma unroll
        for (int ct = 0; ct < 8; ++ct) acc[si][ct] = (f32x4){0.f, 0.f, 0.f, 0.f};
    {
        bf16x8 a[2][4];
#pragma unroll
        for (int si = 0; si < 2; ++si) {
            int row = (wv * 2 + si) * 16 + l16;
#pragma unroll
            for (int kc = 0; kc < 4; ++kc)
                a[si][kc] = *(const bf16x8*)(sAb + row * SST + kc * 32 + q * 8);
        }
#pragma unroll
        for (int kc = 0; kc < 4; ++kc)
#pragma unroll
            for (int ct = 0; ct < 8; ++ct) {
                bf16x8 b = *(const bf16x8*)(Wn2t + (size_t)(ct * 16 + l16) * 128 + kc * 32 + q * 8);
                acc[0][ct] = __builtin_amdgcn_mfma_f32_16x16x32_bf16(a[0][kc], b, acc[0][ct], 0, 0, 0);
                acc[1][ct] = __builtin_amdgcn_mfma_f32_16x16x32_bf16(a[1][kc], b, acc[1][ct], 0, 0, 0);
            }
    }
#pragma unroll
    for (int si = 0; si < 2; ++si)
#pragma unroll
        for (int r = 0; r < 4; ++r) {
            int row = (wv * 2 + si) * 16 + q * 4 + r;
            if (row < nval) {
                float* orow = out_h + (size_t)(n0 + row) * 128;
#pragma unroll
                for (int ct = 0; ct < 8; ++ct)
                    orow[ct * 16 + l16] = acc[si][ct][r] + sBn2[ct * 16 + l16];
            }
        }
}

extern "C" void kernel_launch(void* const* d_in, const int* in_sizes, int n_in,
                              void* d_out, int out_size, void* d_ws, size_t ws_size,
                              hipStream_t stream) {
    const float* h     = (const float*)d_in[0];
    const float* coord = (const float*)d_in[1];
    const float* vel   = (const float*)d_in[2];
    const int*   eidx  = (const int*)d_in[3];
    const float* We1 = (const float*)d_in[4];
    const float* be1 = (const float*)d_in[5];
    const float* We2 = (const float*)d_in[6];
    const float* be2 = (const float*)d_in[7];
    const float* Wc1 = (const float*)d_in[8];
    const float* bc1 = (const float*)d_in[9];
    const float* Wc2 = (const float*)d_in[10];
    const float* bc2 = (const float*)d_in[11];
    const float* Wv1 = (const float*)d_in[12];
    const float* bv1 = (const float*)d_in[13];
    const float* Wv2 = (const float*)d_in[14];
    const float* bv2 = (const float*)d_in[15];
    const float* Wn1 = (const float*)d_in[16];
    const float* bn1 = (const float*)d_in[17];
    const float* Wn2 = (const float*)d_in[18];
    const float* bn2 = (const float*)d_in[19];

    char* ws = (char*)d_ws;
    float* m_acc = (float*)ws;                                  // [NN][128] f32 sigma-packed
    float* c_sum = (float*)(ws + 25600000);                     // [NN][3] f32
    unsigned short* hb   = (unsigned short*)(ws + 26200064);    // [NN][128] bf16
    unsigned short* Wt1  = (unsigned short*)(ws + 39000064);
    unsigned short* Wt2  = (unsigned short*)(ws + 39065600);
    unsigned short* Wt3  = (unsigned short*)(ws + 39098368);
    unsigned short* Wv1t = (unsigned short*)(ws + 39131136);
    unsigned short* Wn1t = (unsigned short*)(ws + 39163904);
    unsigned short* Wn2t = (unsigned short*)(ws + 39229440);
    int* deg    = (int*)(ws + 39262208);                        // [NN]
    int* cursor = (int*)(ws + 39462208);                        // [NN]
    int* rowptr = (int*)(ws + 39662208);                        // [NN+1]
    int* bsum   = (int*)(ws + 39862272);                        // [256]
    int* csr_r  = (int*)(ws + 39863296);                        // [NE]
    int* csr_c  = (int*)(ws + 41863296);                        // [NE]
    unsigned short* P1 = (unsigned short*)(ws + 43863296);      // [NN][128] bf16 sigma
    unsigned short* P2 = (unsigned short*)(ws + 56663296);      // [NN][128] bf16 sigma

    hipMemsetAsync(ws, 0, 26200000, stream);          // m_acc + c_sum
    hipMemsetAsync(ws + 39262208, 0, 400000, stream); // deg + cursor

    prep_h<<<6250, 256, 0, stream>>>(h, hb);
    prep_w<<<512, 256, 0, stream>>>(We1, We2, Wc1, Wv1, Wn1, Wn2,
                                    Wt1, Wt2, Wt3, Wv1t, Wn1t, Wn2t);
    prep_P<<<(NN + 127) / 128, 256, 0, stream>>>(hb, Wt1, P1, P2);

    csr_count<<<1954, 256, 0, stream>>>(eidx, deg);
    scan_a<<<196, 256, 0, stream>>>(deg, bsum);
    scan_b<<<1, 256, 0, stream>>>(bsum);
    scan_c<<<196, 256, 0, stream>>>(deg, bsum, rowptr);
    csr_fill<<<1954, 256, 0, stream>>>(eidx, rowptr, cursor, csr_r, csr_c);

    egcl_edge<<<NEB, 256, 0, stream>>>(
        coord, csr_r, csr_c, P1, P2, Wt2, Wt3,
        We1, be1, be2, bc1, Wc2, bc2, m_acc, c_sum);

    float* out_h = (float*)d_out;
    float* out_c = out_h + (size_t)NN * 128;
    egcl_node<<<(NN + 127) / 128, 256, 0, stream>>>(
        hb, coord, vel, Wv1t, bv1, Wv2, bv2, Wn1t, bn1, Wn2t, bn2,
        m_acc, c_sum, out_h, out_c);
}

// Round 13
// 375.101 us; speedup vs baseline: 1.0699x; 1.0455x over previous
//
#include <hip/hip_runtime.h>
#include <stdint.h>

#define NN 50000
#define NE 500000
#define NEB ((NE + 127) / 128)
#define SST 136   // LDS row stride in shorts (272 B -> 2-way banks on b128 reads)

#define BARRIER() asm volatile("s_waitcnt lgkmcnt(0)\n\ts_barrier" ::: "memory")
#define WAVE_SYNC() asm volatile("s_waitcnt lgkmcnt(0)" ::: "memory")

typedef __attribute__((ext_vector_type(8))) short bf16x8;
typedef __attribute__((ext_vector_type(4))) float f32x4;

// fast silu: x * v_rcp(1+e^-x). 1-instr rcp vs ~8-instr IEEE div; +-1 ulp. (R6)
__device__ __forceinline__ float silu(float x) {
    float e = __expf(-x);
    return x * __builtin_amdgcn_rcpf(1.0f + e);
}
__device__ __forceinline__ float bf2f(unsigned short s) {
    union { unsigned int u; float f; } v; v.u = ((unsigned int)s) << 16; return v.f;
}
__device__ __forceinline__ float bflo(unsigned int u) {   // low bf16 of packed pair
    union { unsigned int u; float f; } v; v.u = u << 16; return v.f;
}
__device__ __forceinline__ float bfhi(unsigned int u) {   // high bf16 of packed pair
    union { unsigned int u; float f; } v; v.u = u & 0xffff0000u; return v.f;
}
__device__ __forceinline__ unsigned short f2bf(float f) {   // RNE (prep only)
    union { float f; unsigned int u; } v; v.f = f;
    return (unsigned short)((v.u + 0x7fffu + ((v.u >> 16) & 1u)) >> 16);
}
// HW packed f32->bf16 (RNE): 1 instr
__device__ __forceinline__ unsigned int pack2(float a, float b) {
    unsigned int r;
    asm("v_cvt_pk_bf16_f32 %0, %1, %2" : "=v"(r) : "v"(a), "v"(b));
    return r;
}
__device__ __forceinline__ bf16x8 packf8(const float* p) {
    float4 f0 = *(const float4*)p; float4 f1 = *(const float4*)(p + 4);
    union { bf16x8 v; unsigned int u[4]; } o;
    o.u[0] = pack2(f0.x, f0.y); o.u[1] = pack2(f0.z, f0.w);
    o.u[2] = pack2(f1.x, f1.y); o.u[3] = pack2(f1.z, f1.w);
    return o.v;
}

// ---------------- fused prep: prep_h + prep_w + csr_count ----------------
// block ranges: [0,6250) h->bf16 | [6250,6762) weight transposes | [6762,8716) deg count
__global__ void prep_all(const float* __restrict__ h, unsigned short* __restrict__ hb,
                         const float* __restrict__ We1, const float* __restrict__ We2,
                         const float* __restrict__ Wc1, const float* __restrict__ Wv1,
                         const float* __restrict__ Wn1, const float* __restrict__ Wn2,
                         unsigned short* __restrict__ Wt1, unsigned short* __restrict__ Wt2,
                         unsigned short* __restrict__ Wt3, unsigned short* __restrict__ Wv1t,
                         unsigned short* __restrict__ Wn1t, unsigned short* __restrict__ Wn2t,
                         const int* __restrict__ eidx, int* __restrict__ deg) {
    int b = blockIdx.x, tid = threadIdx.x;
    if (b < 6250) {
        int i = b * 256 + tid;            // exactly 1,600,000 float4
        float4 v = ((const float4*)h)[i];
        uint2 o; o.x = pack2(v.x, v.y); o.y = pack2(v.z, v.w);
        ((uint2*)hb)[i] = o;
    } else if (b < 6762) {
        int i = (b - 6250) * 256 + tid;
        // sigma(col) = (col%16)*8 + col/16 ; orig_k(ks) = (ks%8)*16 + ks/8
        if (i < 32768) {                                    // Wt1 [128][256] natural
            int j = i >> 8, k = i & 255;
            Wt1[i] = f2bf(We1[k * 128 + j]);
        } else if (i < 49152) {                             // Wt2 [128][128] sigma
            int t = i - 32768; int j = t >> 7, ks = t & 127;
            int k0 = (ks & 7) * 16 + (ks >> 3);
            Wt2[t] = f2bf(We2[k0 * 128 + j]);
        } else if (i < 65536) {                             // Wt3 [128][128] sigma
            int t = i - 49152; int j = t >> 7, ks = t & 127;
            int k0 = (ks & 7) * 16 + (ks >> 3);
            Wt3[t] = f2bf(Wc1[k0 * 128 + j]);
        } else if (i < 81920) {                             // Wv1t [128][128] natural
            int t = i - 65536; int j = t >> 7, k = t & 127;
            Wv1t[t] = f2bf(Wv1[k * 128 + j]);
        } else if (i < 114688) {                            // Wn1t [128][256]: h natural, m sigma
            int t = i - 81920; int j = t >> 8, k = t & 255;
            int ksrc;
            if (k < 128) ksrc = k;
            else { int ks = k - 128; ksrc = 128 + (ks & 7) * 16 + (ks >> 3); }
            Wn1t[t] = f2bf(Wn1[ksrc * 128 + j]);
        } else if (i < 131072) {                            // Wn2t [128][128] sigma
            int t = i - 114688; int j = t >> 7, ks = t & 127;
            int k0 = (ks & 7) * 16 + (ks >> 3);
            Wn2t[t] = f2bf(Wn2[k0 * 128 + j]);
        }
    } else {
        int e = (b - 6762) * 256 + tid;
        if (e < NE) atomicAdd(&deg[eidx[e]], 1);
    }
}

// ---------------- CSR build (2 kernels) ----------------
__global__ void scan_a(const int* __restrict__ deg, int* __restrict__ bsum) {
    __shared__ int s[256];
    int t = threadIdx.x, idx = blockIdx.x * 256 + t;
    s[t] = (idx < NN) ? deg[idx] : 0;
    __syncthreads();
    for (int off = 128; off > 0; off >>= 1) {
        if (t < off) s[t] += s[t + off];
        __syncthreads();
    }
    if (t == 0) bsum[blockIdx.x] = s[0];
}

// scan_b folded in: each block reduces bsum[0..blockIdx) itself (196 ints, trivial)
__global__ void scan_c2(const int* __restrict__ deg, const int* __restrict__ bsum,
                        int* __restrict__ rowptr) {
    __shared__ int sb[256];
    __shared__ int s[256];
    int t = threadIdx.x, b = blockIdx.x, idx = b * 256 + t;
    sb[t] = (t < b) ? bsum[t] : 0;   // b <= 195
    __syncthreads();
    for (int off = 128; off > 0; off >>= 1) {
        if (t < off) sb[t] += sb[t + off];
        __syncthreads();
    }
    int base = sb[0];
    int v = (idx < NN) ? deg[idx] : 0;
    s[t] = v;
    __syncthreads();
    for (int off = 1; off < 256; off <<= 1) {
        int x = (t >= off) ? s[t - off] : 0;
        __syncthreads();
        s[t] += x;
        __syncthreads();
    }
    if (idx < NN) rowptr[idx] = base + s[t] - v;
    if (idx == 0) rowptr[NN] = NE;
}

// cursor-free fill: atomicSub on deg (deg dead afterwards); single int2 store
__global__ void csr_fill(const int* __restrict__ eidx, const int* __restrict__ rowptr,
                         int* __restrict__ deg, int2* __restrict__ csr_rc) {
    int e = blockIdx.x * 256 + threadIdx.x;
    if (e < NE) {
        int r = eidx[e], c = eidx[NE + e];
        int slot = rowptr[r] + atomicSub(&deg[r], 1) - 1;
        csr_rc[slot] = make_int2(r, c);
    }
}

// ---------------- helpers (256-thread staging) ----------------
__device__ __forceinline__ void stage256(const unsigned short* __restrict__ W, int halfk,
                                         unsigned short* sW, int tid) {
#pragma unroll
    for (int t = 0; t < 8; ++t) {
        int idx = tid + t * 256; int j = idx >> 4, g = idx & 15;
        *(uint4*)(sW + j * SST + g * 8) = *(const uint4*)(W + (size_t)j * 256 + halfk * 128 + g * 8);
    }
}
__device__ __forceinline__ void stage128(const unsigned short* __restrict__ W,
                                         unsigned short* sW, int tid) {
#pragma unroll
    for (int t = 0; t < 8; ++t) {
        int idx = tid + t * 256; int j = idx >> 4, g = idx & 15;
        *(uint4*)(sW + j * SST + g * 8) = *(const uint4*)(W + (size_t)j * 128 + g * 8);
    }
}
__device__ __forceinline__ void mfma4(const bf16x8 a[2][4], const unsigned short* sW,
                                      int l16, int q, f32x4 acc[2][8]) {
#pragma unroll
    for (int kc = 0; kc < 4; ++kc)
#pragma unroll
        for (int ct = 0; ct < 8; ++ct) {
            bf16x8 b = *(const bf16x8*)(sW + (ct * 16 + l16) * SST + kc * 32 + q * 8);
            acc[0][ct] = __builtin_amdgcn_mfma_f32_16x16x32_bf16(a[0][kc], b, acc[0][ct], 0, 0, 0);
            acc[1][ct] = __builtin_amdgcn_mfma_f32_16x16x32_bf16(a[1][kc], b, acc[1][ct], 0, 0, 0);
        }
}

// ---------------- prep_P: per-NODE halves of e1 ----------------
// P1[n] = h[n] @ We1[0:128], P2[n] = h[n] @ We1[128:256]; stored bf16
// SIGMA-packed so the edge kernel gathers them directly as e2 A-fragments.
__global__ __launch_bounds__(256, 2) void prep_P(
    const unsigned short* __restrict__ hb,
    const unsigned short* __restrict__ Wt1,
    unsigned short* __restrict__ P1, unsigned short* __restrict__ P2)
{
    __shared__ __align__(16) unsigned short sWa[128 * SST];
    __shared__ __align__(16) unsigned short sWb[128 * SST];
    const int tid = threadIdx.x;
    const int wv = tid >> 6, lane = tid & 63, q = lane >> 4, l16 = lane & 15;
    const int n0 = blockIdx.x * 128;

    stage256(Wt1, 0, sWa, tid);
    stage256(Wt1, 1, sWb, tid);
    bf16x8 ah[2][4];
#pragma unroll
    for (int si = 0; si < 2; ++si) {
        int nn = n0 + (wv * 2 + si) * 16 + l16; if (nn >= NN) nn = NN - 1;
#pragma unroll
        for (int kc = 0; kc < 4; ++kc)
            ah[si][kc] = *(const bf16x8*)(hb + (size_t)nn * 128 + kc * 32 + q * 8);
    }
    BARRIER();

    f32x4 acc[2][8];
#pragma unroll
    for (int si = 0; si < 2; ++si)
#pragma unroll
        for (int ct = 0; ct < 8; ++ct) acc[si][ct] = (f32x4){0.f, 0.f, 0.f, 0.f};
    mfma4(ah, sWa, l16, q, acc);
#pragma unroll
    for (int si = 0; si < 2; ++si)
#pragma unroll
        for (int r = 0; r < 4; ++r) {
            int n = n0 + (wv * 2 + si) * 16 + q * 4 + r;
            if (n < NN) {
                uint4 pk = make_uint4(pack2(acc[si][0][r], acc[si][1][r]),
                                      pack2(acc[si][2][r], acc[si][3][r]),
                                      pack2(acc[si][4][r], acc[si][5][r]),
                                      pack2(acc[si][6][r], acc[si][7][r]));
                *(uint4*)(P1 + (size_t)n * 128 + l16 * 8) = pk;
            }
        }
#pragma unroll
    for (int si = 0; si < 2; ++si)
#pragma unroll
        for (int ct = 0; ct < 8; ++ct) acc[si][ct] = (f32x4){0.f, 0.f, 0.f, 0.f};
    mfma4(ah, sWb, l16, q, acc);
#pragma unroll
    for (int si = 0; si < 2; ++si)
#pragma unroll
        for (int r = 0; r < 4; ++r) {
            int n = n0 + (wv * 2 + si) * 16 + q * 4 + r;
            if (n < NN) {
                uint4 pk = make_uint4(pack2(acc[si][0][r], acc[si][1][r]),
                                      pack2(acc[si][2][r], acc[si][3][r]),
                                      pack2(acc[si][4][r], acc[si][5][r]),
                                      pack2(acc[si][6][r], acc[si][7][r]));
                *(uint4*)(P2 + (size_t)n * 128 + l16 * 8) = pk;
            }
        }
}

// ---------------- edge kernel: e1 eliminated (P-gather), 2 GEMM stages ------
// t1 built in registers from P1[r]+P2[c]+rad*wlast+be1 (wlast/be1 sigma-
// permuted so k-order matches sigma-staged Wt2). 3 barriers.
// sM: Wt2 -> (after B) m; sB3: Wt3. 2 blocks/CU (proven optimum; occupancy
// experiments R4/R8/R9/R11 all null-or-negative on this kernel family).
__global__ __launch_bounds__(256, 2) void egcl_edge(
    const float* __restrict__ coord,
    const int2* __restrict__ csr_rc,
    const unsigned short* __restrict__ P1, const unsigned short* __restrict__ P2,
    const unsigned short* __restrict__ Wt2, const unsigned short* __restrict__ Wt3,
    const float* __restrict__ We1,
    const float* __restrict__ be1, const float* __restrict__ be2,
    const float* __restrict__ bc1,
    const float* __restrict__ Wc2, const float* __restrict__ bc2,
    float* __restrict__ m_acc, float* __restrict__ c_sum)
{
    __shared__ __align__(16) unsigned short sM[128 * SST];
    __shared__ __align__(16) unsigned short sB3[128 * SST];
    __shared__ float sRad[128], sDif[128][3];
    __shared__ int sSeg[128];
    __shared__ float sWlS[128], sBe1S[128], sBe2[128], sBc1[128], sWc2f[128];

    const int tid = threadIdx.x;
    const int wv = tid >> 6, lane = tid & 63, q = lane >> 4, l16 = lane & 15;
    const int e0 = blockIdx.x * 128;

    int nr[2], nc[2];
#pragma unroll
    for (int si = 0; si < 2; ++si) {
        int e = e0 + (wv * 2 + si) * 16 + l16;
        if (e >= NE) e = NE - 1;
        int2 rc = csr_rc[e];
        nr[si] = rc.x; nc[si] = rc.y;
    }
    // gather P fragments early (replaces h-gather 1:1)
    bf16x8 pr[2][4], pc[2][4];
#pragma unroll
    for (int si = 0; si < 2; ++si)
#pragma unroll
        for (int kc = 0; kc < 4; ++kc) {
            pr[si][kc] = *(const bf16x8*)(P1 + (size_t)nr[si] * 128 + kc * 32 + q * 8);
            pc[si][kc] = *(const bf16x8*)(P2 + (size_t)nc[si] * 128 + kc * 32 + q * 8);
        }

    if (tid < 128) {
        // sigma-permute wlast/be1: orig_k(m) = (m%8)*16 + m/8
        int k0 = (tid & 7) * 16 + (tid >> 3);
        sWlS[tid] = We1[256 * 128 + k0]; sBe1S[tid] = be1[k0];
        sBe2[tid] = be2[tid]; sBc1[tid] = bc1[tid]; sWc2f[tid] = Wc2[tid];
        int s = e0 + tid; int sc = (s < NE) ? s : (NE - 1);
        int2 rc = csr_rc[sc];
        int r = rc.x, c = rc.y;
        sSeg[tid] = (s < NE) ? r : -1;
        float dx = coord[r * 3 + 0] - coord[c * 3 + 0];
        float dy = coord[r * 3 + 1] - coord[c * 3 + 1];
        float dz = coord[r * 3 + 2] - coord[c * 3 + 2];
        float rad = fmaf(dx, dx, fmaf(dy, dy, dz * dz));
        float inv = 1.0f / (sqrtf(rad) + 1e-8f);
        sRad[tid] = rad;
        sDif[tid][0] = dx * inv; sDif[tid][1] = dy * inv; sDif[tid][2] = dz * inv;
    }
    stage128(Wt2, sM, tid);
    stage128(Wt3, sB3, tid);
    const float bc2v = bc2[0];
    BARRIER();   // A: geometry + Wt2(sM) + Wt3(sB3) + sigma'd wlast/be1 visible

    // ---- t1 build in registers: silu(P1[r] + P2[c] + rad*wl + be1)
    bf16x8 a[2][4];
#pragma unroll
    for (int si = 0; si < 2; ++si) {
        int row = (wv * 2 + si) * 16 + l16;
        float rad = sRad[row];
#pragma unroll
        for (int kc = 0; kc < 4; ++kc) {
            const float* wl = sWlS + kc * 32 + q * 8;
            const float* be = sBe1S + kc * 32 + q * 8;
            union { bf16x8 v; unsigned int u[4]; } R, C;
            R.v = pr[si][kc]; C.v = pc[si][kc];
            float t[8];
#pragma unroll
            for (int p = 0; p < 4; ++p) {
                t[2 * p]     = bflo(R.u[p]) + bflo(C.u[p]);
                t[2 * p + 1] = bfhi(R.u[p]) + bfhi(C.u[p]);
            }
#pragma unroll
            for (int j = 0; j < 8; ++j)
                t[j] = silu(fmaf(rad, wl[j], t[j] + be[j]));
            union { bf16x8 v; unsigned int u[4]; } O;
            O.u[0] = pack2(t[0], t[1]); O.u[1] = pack2(t[2], t[3]);
            O.u[2] = pack2(t[4], t[5]); O.u[3] = pack2(t[6], t[7]);
            a[si][kc] = O.v;
        }
    }

    // ---- e2: m = silu(t1 @ We2 + be2), B = Wt2 (sM)
    f32x4 acc[2][8];
#pragma unroll
    for (int si = 0; si < 2; ++si)
#pragma unroll
        for (int ct = 0; ct < 8; ++ct) acc[si][ct] = (f32x4){0.f, 0.f, 0.f, 0.f};
    mfma4(a, sM, l16, q, acc);
    uint4 mu[2][4];
#pragma unroll
    for (int si = 0; si < 2; ++si)
#pragma unroll
        for (int r = 0; r < 4; ++r) {
            float v[8];
#pragma unroll
            for (int ct = 0; ct < 8; ++ct) v[ct] = silu(acc[si][ct][r] + sBe2[ct * 16 + l16]);
            mu[si][r] = make_uint4(pack2(v[0], v[1]), pack2(v[2], v[3]),
                                   pack2(v[4], v[5]), pack2(v[6], v[7]));
        }
    BARRIER();   // B: all waves' Wt2 reads done -> sM reusable for m
#pragma unroll
    for (int si = 0; si < 2; ++si)
#pragma unroll
        for (int r = 0; r < 4; ++r) {
            int row = (wv * 2 + si) * 16 + q * 4 + r;
            *(uint4*)(sM + row * SST + l16 * 8) = mu[si][r];
        }
    WAVE_SYNC();  // own-wave m rows visible for own c1 A-reads (wave-private)

    // ---- c1: A = m (own rows, sM), B = Wt3 (sB3)
#pragma unroll
    for (int si = 0; si < 2; ++si)
#pragma unroll
        for (int ct = 0; ct < 8; ++ct) acc[si][ct] = (f32x4){0.f, 0.f, 0.f, 0.f};
    {
        bf16x8 am[2][4];
#pragma unroll
        for (int si = 0; si < 2; ++si) {
            int row = (wv * 2 + si) * 16 + l16;
#pragma unroll
            for (int kc = 0; kc < 4; ++kc)
                am[si][kc] = *(const bf16x8*)(sM + row * SST + kc * 32 + q * 8);
        }
        mfma4(am, sB3, l16, q, acc);
    }
    // c2: silu -> dot Wc2 -> 16-lane reduce -> c_sum atomics
#pragma unroll
    for (int si = 0; si < 2; ++si) {
        float p[4];
#pragma unroll
        for (int r = 0; r < 4; ++r) {
            float s = 0.f;
#pragma unroll
            for (int ct = 0; ct < 8; ++ct) {
                int col = ct * 16 + l16;
                float t = silu(acc[si][ct][r] + sBc1[col]);
                s = fmaf(t, sWc2f[col], s);
            }
            p[r] = s;
        }
#pragma unroll
        for (int m = 1; m < 16; m <<= 1)
#pragma unroll
            for (int r = 0; r < 4; ++r) p[r] += __shfl_xor(p[r], m, 16);
        if (l16 == 0) {
#pragma unroll
            for (int r = 0; r < 4; ++r) {
                int row = (wv * 2 + si) * 16 + q * 4 + r;
                int rn = sSeg[row];
                if (rn >= 0) {
                    float wgt = p[r] + bc2v;
                    atomicAdd(&c_sum[(size_t)rn * 3 + 0], sDif[row][0] * wgt);
                    atomicAdd(&c_sum[(size_t)rn * 3 + 1], sDif[row][1] * wgt);
                    atomicAdd(&c_sum[(size_t)rn * 3 + 2], sDif[row][2] * wgt);
                }
            }
        }
    }
    BARRIER();   // C: all waves' m rows visible for cross-wave reduce

    // ---- segmented m reduction (reads sM), batch-4
    {
        int p = tid & 127, half = tid >> 7;
        int base = half * 64;
        float run = 0.f;
        int cur = sSeg[base];
        bool openL = true;   // current run touches segment start (may continue left)
#pragma unroll 1
        for (int i0 = 0; i0 < 64; i0 += 4) {
            float v[4]; int rr[4];
#pragma unroll
            for (int j = 0; j < 4; ++j) {
                int row = base + i0 + j;
                rr[j] = sSeg[row];
                v[j] = bf2f(sM[row * SST + p]);
            }
#pragma unroll
            for (int j = 0; j < 4; ++j) {
                if (rr[j] != cur) {
                    if (cur >= 0) {
                        float* dst = &m_acc[(size_t)cur * 128 + p];
                        if (openL) atomicAdd(dst, run);
                        else       *dst = run;   // interior run: exclusive writer
                    }
                    run = 0.f; cur = rr[j]; openL = false;
                }
                run += v[j];
            }
        }
        if (cur >= 0) atomicAdd(&m_acc[(size_t)cur * 128 + p], run);  // open at right
    }
}

// ---------------- node kernel: MFMA vel-MLP + node-MLP (R6 unchanged) ----------------
__global__ __launch_bounds__(256, 3) void egcl_node(
    const unsigned short* __restrict__ hb,
    const float* __restrict__ coord,
    const float* __restrict__ vel,
    const unsigned short* __restrict__ Wv1t, const float* __restrict__ bv1,
    const float* __restrict__ Wv2, const float* __restrict__ bv2,
    const unsigned short* __restrict__ Wn1t, const float* __restrict__ bn1,
    const unsigned short* __restrict__ Wn2t, const float* __restrict__ bn2,
    const float* __restrict__ m_acc, const float* __restrict__ c_sum,
    float* __restrict__ out_h, float* __restrict__ out_c)
{
    __shared__ __align__(16) unsigned short sAb[128 * SST];
    __shared__ float sBv1[128], sWv2f[128], sBn1[128], sBn2[128];

    const int tid = threadIdx.x;
    const int wv = tid >> 6, lane = tid & 63, q = lane >> 4, l16 = lane & 15;
    const int n0 = blockIdx.x * 128;
    int nval = NN - n0; if (nval > 128) nval = 128;

    if (tid < 128) {
        sBv1[tid] = bv1[tid]; sWv2f[tid] = Wv2[tid];
        sBn1[tid] = bn1[tid]; sBn2[tid] = bn2[tid];
    }
    const float bv2v = bv2[0];

    bf16x8 ah[2][4], am[2][4];   // am reads sigma-packed m_acc; Wn1t m-half is sigma'd
#pragma unroll
    for (int si = 0; si < 2; ++si) {
        int row = (wv * 2 + si) * 16 + l16;
        int nn = n0 + row; if (nn >= NN) nn = NN - 1;
#pragma unroll
        for (int kc = 0; kc < 4; ++kc) {
            ah[si][kc] = *(const bf16x8*)(hb + (size_t)nn * 128 + kc * 32 + q * 8);
            am[si][kc] = packf8(m_acc + (size_t)nn * 128 + kc * 32 + q * 8);
        }
    }

    BARRIER();   // biases visible

    f32x4 acc[2][8];
    // ---- vel MLP
#pragma unroll
    for (int si = 0; si < 2; ++si)
#pragma unroll
        for (int ct = 0; ct < 8; ++ct) acc[si][ct] = (f32x4){0.f, 0.f, 0.f, 0.f};
#pragma unroll
    for (int kc = 0; kc < 4; ++kc)
#pragma unroll
        for (int ct = 0; ct < 8; ++ct) {
            bf16x8 b = *(const bf16x8*)(Wv1t + (size_t)(ct * 16 + l16) * 128 + kc * 32 + q * 8);
            acc[0][ct] = __builtin_amdgcn_mfma_f32_16x16x32_bf16(ah[0][kc], b, acc[0][ct], 0, 0, 0);
            acc[1][ct] = __builtin_amdgcn_mfma_f32_16x16x32_bf16(ah[1][kc], b, acc[1][ct], 0, 0, 0);
        }
#pragma unroll
    for (int si = 0; si < 2; ++si) {
        float p[4];
#pragma unroll
        for (int r = 0; r < 4; ++r) {
            float s = 0.f;
#pragma unroll
            for (int ct = 0; ct < 8; ++ct) {
                int col = ct * 16 + l16;
                float t = silu(acc[si][ct][r] + sBv1[col]);
                s = fmaf(t, sWv2f[col], s);
            }
            p[r] = s;
        }
#pragma unroll
        for (int m = 1; m < 16; m <<= 1)
#pragma unroll
            for (int r = 0; r < 4; ++r) p[r] += __shfl_xor(p[r], m, 16);
        if (l16 == 0) {
#pragma unroll
            for (int r = 0; r < 4; ++r) {
                int row = (wv * 2 + si) * 16 + q * 4 + r;
                int n = n0 + row;
                if (row < nval) {
                    float vw = p[r] + bv2v;
#pragma unroll
                    for (int d = 0; d < 3; ++d) {
                        float cv = coord[(size_t)n * 3 + d] + c_sum[(size_t)n * 3 + d]
                                 + vel[(size_t)n * 3 + d] * vw;
                        out_c[(size_t)n * 3 + d] = cv;
                    }
                }
            }
        }
    }

    // ---- n1: K=256 on [h | m_i]
#pragma unroll
    for (int si = 0; si < 2; ++si)
#pragma unroll
        for (int ct = 0; ct < 8; ++ct) acc[si][ct] = (f32x4){0.f, 0.f, 0.f, 0.f};
#pragma unroll
    for (int kc = 0; kc < 8; ++kc)
#pragma unroll
        for (int ct = 0; ct < 8; ++ct) {
            bf16x8 b = *(const bf16x8*)(Wn1t + (size_t)(ct * 16 + l16) * 256 + kc * 32 + q * 8);
            bf16x8 a0 = (kc < 4) ? ah[0][kc & 3] : am[0][kc & 3];
            bf16x8 a1 = (kc < 4) ? ah[1][kc & 3] : am[1][kc & 3];
            acc[0][ct] = __builtin_amdgcn_mfma_f32_16x16x32_bf16(a0, b, acc[0][ct], 0, 0, 0);
            acc[1][ct] = __builtin_amdgcn_mfma_f32_16x16x32_bf16(a1, b, acc[1][ct], 0, 0, 0);
        }
#pragma unroll
    for (int si = 0; si < 2; ++si)
#pragma unroll
        for (int r = 0; r < 4; ++r) {
            int row = (wv * 2 + si) * 16 + q * 4 + r;
            float v[8];
#pragma unroll
            for (int ct = 0; ct < 8; ++ct) v[ct] = silu(acc[si][ct][r] + sBn1[ct * 16 + l16]);
            uint4 pk = make_uint4(pack2(v[0], v[1]), pack2(v[2], v[3]),
                                  pack2(v[4], v[5]), pack2(v[6], v[7]));
            *(uint4*)(sAb + row * SST + l16 * 8) = pk;
        }

    BARRIER();   // t1 visible

    // ---- n2
#pragma unroll
    for (int si = 0; si < 2; ++si)
#pragma unroll
        for (int ct = 0; ct < 8; ++ct) acc[si][ct] = (f32x4){0.f, 0.f, 0.f, 0.f};
    {
        bf16x8 a[2][4];
#pragma unroll
        for (int si = 0; si < 2; ++si) {
            int row = (wv * 2 + si) * 16 + l16;
#pragma unroll
            for (int kc = 0; kc < 4; ++kc)
                a[si][kc] = *(const bf16x8*)(sAb + row * SST + kc * 32 + q * 8);
        }
#pragma unroll
        for (int kc = 0; kc < 4; ++kc)
#pragma unroll
            for (int ct = 0; ct < 8; ++ct) {
                bf16x8 b = *(const bf16x8*)(Wn2t + (size_t)(ct * 16 + l16) * 128 + kc * 32 + q * 8);
                acc[0][ct] = __builtin_amdgcn_mfma_f32_16x16x32_bf16(a[0][kc], b, acc[0][ct], 0, 0, 0);
                acc[1][ct] = __builtin_amdgcn_mfma_f32_16x16x32_bf16(a[1][kc], b, acc[1][ct], 0, 0, 0);
            }
    }
#pragma unroll
    for (int si = 0; si < 2; ++si)
#pragma unroll
        for (int r = 0; r < 4; ++r) {
            int row = (wv * 2 + si) * 16 + q * 4 + r;
            if (row < nval) {
                float* orow = out_h + (size_t)(n0 + row) * 128;
#pragma unroll
                for (int ct = 0; ct < 8; ++ct)
                    orow[ct * 16 + l16] = acc[si][ct][r] + sBn2[ct * 16 + l16];
            }
        }
}

extern "C" void kernel_launch(void* const* d_in, const int* in_sizes, int n_in,
                              void* d_out, int out_size, void* d_ws, size_t ws_size,
                              hipStream_t stream) {
    const float* h     = (const float*)d_in[0];
    const float* coord = (const float*)d_in[1];
    const float* vel   = (const float*)d_in[2];
    const int*   eidx  = (const int*)d_in[3];
    const float* We1 = (const float*)d_in[4];
    const float* be1 = (const float*)d_in[5];
    const float* We2 = (const float*)d_in[6];
    const float* be2 = (const float*)d_in[7];
    const float* Wc1 = (const float*)d_in[8];
    const float* bc1 = (const float*)d_in[9];
    const float* Wc2 = (const float*)d_in[10];
    const float* bc2 = (const float*)d_in[11];
    const float* Wv1 = (const float*)d_in[12];
    const float* bv1 = (const float*)d_in[13];
    const float* Wv2 = (const float*)d_in[14];
    const float* bv2 = (const float*)d_in[15];
    const float* Wn1 = (const float*)d_in[16];
    const float* bn1 = (const float*)d_in[17];
    const float* Wn2 = (const float*)d_in[18];
    const float* bn2 = (const float*)d_in[19];

    char* ws = (char*)d_ws;
    float* m_acc = (float*)ws;                                  // [NN][128] f32 sigma-packed
    float* c_sum = (float*)(ws + 25600000);                     // [NN][3] f32
    unsigned short* hb   = (unsigned short*)(ws + 26200064);    // [NN][128] bf16
    unsigned short* Wt1  = (unsigned short*)(ws + 39000064);
    unsigned short* Wt2  = (unsigned short*)(ws + 39065600);
    unsigned short* Wt3  = (unsigned short*)(ws + 39098368);
    unsigned short* Wv1t = (unsigned short*)(ws + 39131136);
    unsigned short* Wn1t = (unsigned short*)(ws + 39163904);
    unsigned short* Wn2t = (unsigned short*)(ws + 39229440);
    int* deg    = (int*)(ws + 39262208);                        // [NN]
    int* rowptr = (int*)(ws + 39662208);                        // [NN+1]
    int* bsum   = (int*)(ws + 39862272);                        // [256]
    int2* csr_rc = (int2*)(ws + 39863296);                      // [NE] int2 (4 MB)
    unsigned short* P1 = (unsigned short*)(ws + 43863296);      // [NN][128] bf16 sigma
    unsigned short* P2 = (unsigned short*)(ws + 56663296);      // [NN][128] bf16 sigma

    hipMemsetAsync(ws, 0, 26200000, stream);   // m_acc + c_sum (DMA path)
    hipMemsetAsync(deg, 0, 200000, stream);    // deg only (cursor eliminated)

    prep_all<<<8716, 256, 0, stream>>>(h, hb, We1, We2, Wc1, Wv1, Wn1, Wn2,
                                       Wt1, Wt2, Wt3, Wv1t, Wn1t, Wn2t,
                                       eidx, deg);
    prep_P<<<(NN + 127) / 128, 256, 0, stream>>>(hb, Wt1, P1, P2);

    scan_a<<<196, 256, 0, stream>>>(deg, bsum);
    scan_c2<<<196, 256, 0, stream>>>(deg, bsum, rowptr);
    csr_fill<<<1954, 256, 0, stream>>>(eidx, rowptr, deg, csr_rc);

    egcl_edge<<<NEB, 256, 0, stream>>>(
        coord, csr_rc, P1, P2, Wt2, Wt3,
        We1, be1, be2, bc1, Wc2, bc2, m_acc, c_sum);

    float* out_h = (float*)d_out;
    float* out_c = out_h + (size_t)NN * 128;
    egcl_node<<<(NN + 127) / 128, 256, 0, stream>>>(
        hb, coord, vel, Wv1t, bv1, Wv2, bv2, Wn1t, bn1, Wn2t, bn2,
        m_acc, c_sum, out_h, out_c);
}